// Round 3
// baseline (278.069 us; speedup 1.0000x reference)
//
#include <hip/hip_runtime.h>

#define BATCH 2048
#define SIZE 4096
#define DOWN 256
#define NTASK 16
#define KC 16
#define KCHUNK (SIZE / KC)  // 256

typedef _Float16 half8 __attribute__((ext_vector_type(8)));
typedef float floatx4 __attribute__((ext_vector_type(4)));

__device__ __forceinline__ int imin(int a, int b) { return a < b ? a : b; }

// async global->LDS, 16B per lane. LDS dest is wave-uniform base + lane*16
// (hardware scatter); global src is per-lane.
__device__ __forceinline__ void async16(void* lds, const void* g) {
    __builtin_amdgcn_global_load_lds((const __attribute__((address_space(1))) unsigned int*)g,
                                     (__attribute__((address_space(3))) unsigned int*)lds,
                                     16, 0, 0);
}

// ---------------- counting sort (standalone, for fallback path) ----------------
__device__ __forceinline__ void sort_body(const int* __restrict__ task_id,
                                          int* __restrict__ taskOff,
                                          int* __restrict__ sortedIdx,
                                          int* __restrict__ taskOfPos) {
    __shared__ int cnt[NTASK];
    __shared__ int base[NTASK + 1];
    __shared__ int cur[NTASK];
    int tid = threadIdx.x;
    if (tid < NTASK) cnt[tid] = 0;
    __syncthreads();
    for (int i = tid; i < BATCH; i += 256) atomicAdd(&cnt[task_id[i]], 1);
    __syncthreads();
    if (tid == 0) {
        int s = 0;
        for (int t = 0; t < NTASK; t++) { base[t] = s; s += cnt[t]; }
        base[NTASK] = s;
    }
    __syncthreads();
    if (tid < NTASK) { cur[tid] = base[tid]; taskOff[tid] = base[tid]; }
    if (tid == 0) taskOff[NTASK] = BATCH;
    __syncthreads();
    for (int i = tid; i < BATCH; i += 256) {
        int t = task_id[i];
        int p = atomicAdd(&cur[t], 1);
        sortedIdx[p] = i;
        taskOfPos[p] = t;
    }
}

__global__ __launch_bounds__(256) void sort_kernel(const int* __restrict__ task_id,
                                                   int* __restrict__ taskOff,
                                                   int* __restrict__ sortedIdx,
                                                   int* __restrict__ taskOfPos) {
    sort_body(task_id, taskOff, sortedIdx, taskOfPos);
}

// ---------------- prep: sort (block 0) + pack Wd/Wu -> fp16 k-pack-8 tiles ----
// Wd16 tile (t, ks64 in 0..63): 64 k x 256 n as half8[kg=8][n=256] (32 KB).
// Wu16 tile (t, nt in 0..15, ks64 in 0..3): same shape from Wu[.., nt*256..].
// A GEMM kstep (BK=32) is one contiguous 16 KB half of a tile.
__global__ __launch_bounds__(256) void prep_kernel(const int* __restrict__ task_id,
                                                   int* __restrict__ taskOff,
                                                   int* __restrict__ sortedIdx,
                                                   int* __restrict__ taskOfPos,
                                                   const float* __restrict__ Wd,
                                                   const float* __restrict__ Wu,
                                                   _Float16* __restrict__ Wd16,
                                                   _Float16* __restrict__ Wu16) {
    int b = blockIdx.x;
    if (b == 0) {
        sort_body(task_id, taskOff, sortedIdx, taskOfPos);
        return;
    }
    int tid = threadIdx.x, w = tid >> 6, lane = tid & 63;
    const float* src;
    _Float16* dst;
    size_t rstride;
    if (b <= 1024) {  // Wd tiles
        int i = b - 1, t = i >> 6, ks = i & 63;
        src = Wd + ((size_t)t * SIZE + ks * 64) * DOWN;
        dst = Wd16 + (size_t)(t * 64 + ks) * 16384;
        rstride = DOWN;
    } else {  // Wu tiles
        int i = b - 1025, t = i >> 6, nt = (i >> 2) & 15, ks = i & 3;
        src = Wu + ((size_t)t * DOWN + ks * 64) * SIZE + nt * 256;
        dst = Wu16 + (size_t)((t * 16 + nt) * 4 + ks) * 16384;
        rstride = SIZE;
    }
#pragma unroll
    for (int kk = 0; kk < 2; kk++) {
        int kg = w * 2 + kk;
        float f[8][4];
#pragma unroll
        for (int e = 0; e < 8; e++)
#pragma unroll
            for (int j = 0; j < 4; j++)
                f[e][j] = src[(size_t)(kg * 8 + e) * rstride + j * 64 + lane];
#pragma unroll
        for (int j = 0; j < 4; j++) {
            half8 h;
#pragma unroll
            for (int e = 0; e < 8; e++) h[e] = (_Float16)f[e][j];
            *(half8*)(dst + (size_t)(kg * 256 + j * 64 + lane) * 8) = h;
        }
    }
}

// ---------------- GEMM1: partial[kc][pos][h] = x[rows(t)] @ Wd16[t] ------------
// M=64 x N=256 per block (wave n-strips of 64), BK=32, 8 ksteps per kc chunk.
// B staged via global_load_lds (zero VGPR); A (fp32 x, gathered rows) via thin
// reg path (8 VGPR, load-early/write-late), converted at fragment-read time.
// One-deep prefetch, one __syncthreads per kstep (m97/T3-minimum structure).
__global__ __launch_bounds__(256, 3) void gemm1_kernel(const float* __restrict__ x,
                                                       const _Float16* __restrict__ Wd16,
                                                       const int* __restrict__ taskOff,
                                                       const int* __restrict__ sortedIdx,
                                                       _Float16* __restrict__ partial) {
    int task = blockIdx.x >> 1, z = blockIdx.x & 1, kc = blockIdx.y;
    int rowStart = taskOff[task];
    int nrows = taskOff[task + 1] - rowStart;
    if (nrows <= 0) return;

    __shared__ floatx4 Af[2][64][8];   // [buf][row][chunk^], 8 KB/buf (fp32, BK=32)
    __shared__ half8 Bp[2][4][256];    // [buf][kg][n], 16 KB/buf

    int tid = threadIdx.x;
    int wave = tid >> 6, lane = tid & 63, quad = lane >> 4, l15 = lane & 15;
    int arow = tid >> 2, c4 = tid & 3;
    int kcbase = kc * KCHUNK;

    for (int r0 = z * 64; r0 < nrows; r0 += 128) {
        int asrc = sortedIdx[rowStart + imin(r0 + arow, nrows - 1)];
        const float* xrow = x + (size_t)asrc * SIZE + kcbase;

        // ---- prologue: stage kstep 0 into buf 0 ----
        {
            const char* tb = (const char*)Wd16 +
                             (((size_t)task * 64 + kc * 4) << 15);  // ts=0: half 0
#pragma unroll
            for (int i = 0; i < 4; i++)
                async16((char*)(&Bp[0][0][0]) + (wave * 4 + i) * 1024,
                        tb + (wave * 4 + i) * 1024 + lane * 16);
            floatx4 f0 = *(const floatx4*)(xrow + c4 * 8);
            floatx4 f1 = *(const floatx4*)(xrow + c4 * 8 + 4);
            Af[0][arow][(c4 * 2) ^ (arow & 7)] = f0;
            Af[0][arow][(c4 * 2 + 1) ^ (arow & 7)] = f1;
        }
        __syncthreads();

        floatx4 acc[4][4];
#pragma unroll
        for (int mi = 0; mi < 4; mi++)
#pragma unroll
            for (int ni = 0; ni < 4; ni++) acc[mi][ni] = (floatx4){0.f, 0.f, 0.f, 0.f};

        int buf = 0;
        for (int ts = 0; ts < 8; ts++) {
            floatx4 f0, f1;
            if (ts < 7) {
                // issue next kstep: B via glds, A into regs (write-late)
                int tn = ts + 1;
                const char* tb = (const char*)Wd16 +
                                 (((size_t)task * 64 + kc * 4 + (tn >> 1)) << 15) +
                                 ((size_t)(tn & 1) << 14);
#pragma unroll
                for (int i = 0; i < 4; i++)
                    async16((char*)(&Bp[buf ^ 1][0][0]) + (wave * 4 + i) * 1024,
                            tb + (wave * 4 + i) * 1024 + lane * 16);
                f0 = *(const floatx4*)(xrow + tn * 32 + c4 * 8);
                f1 = *(const floatx4*)(xrow + tn * 32 + c4 * 8 + 4);
            }
            // ---- compute kstep ts from buf ----
            half8 a[4], bfr[4];
#pragma unroll
            for (int mi = 0; mi < 4; mi++) {
                int row = mi * 16 + l15, s7 = row & 7;
                floatx4 u0 = Af[buf][row][(quad * 2) ^ s7];
                floatx4 u1 = Af[buf][row][(quad * 2 + 1) ^ s7];
                half8 h;
                h[0] = (_Float16)u0[0]; h[1] = (_Float16)u0[1];
                h[2] = (_Float16)u0[2]; h[3] = (_Float16)u0[3];
                h[4] = (_Float16)u1[0]; h[5] = (_Float16)u1[1];
                h[6] = (_Float16)u1[2]; h[7] = (_Float16)u1[3];
                a[mi] = h;
            }
#pragma unroll
            for (int ni = 0; ni < 4; ni++)
                bfr[ni] = Bp[buf][quad][wave * 64 + ni * 16 + l15];
#pragma unroll
            for (int mi = 0; mi < 4; mi++)
#pragma unroll
                for (int ni = 0; ni < 4; ni++)
                    acc[mi][ni] = __builtin_amdgcn_mfma_f32_16x16x32_f16(
                        a[mi], bfr[ni], acc[mi][ni], 0, 0, 0);
            if (ts < 7) {  // write-late A stage (loads had whole compute to land)
                Af[buf ^ 1][arow][(c4 * 2) ^ (arow & 7)] = f0;
                Af[buf ^ 1][arow][(c4 * 2 + 1) ^ (arow & 7)] = f1;
            }
            __syncthreads();
            buf ^= 1;
        }
        // ---- epilogue: partial[kc][rowStart+r][h], fp16 ----
#pragma unroll
        for (int mi = 0; mi < 4; mi++) {
#pragma unroll
            for (int reg = 0; reg < 4; reg++) {
                int r = r0 + mi * 16 + quad * 4 + reg;
                if (r < nrows) {
                    size_t rowoff = ((size_t)kc * BATCH + (rowStart + r)) * DOWN;
#pragma unroll
                    for (int ni = 0; ni < 4; ni++) {
                        int h = wave * 64 + ni * 16 + l15;
                        partial[rowoff + h] = (_Float16)acc[mi][ni][reg];
                    }
                }
            }
        }
    }
}

// ---------------- SiLU: act[s][h] = silu(sum_kc partial + bd) ----------------
__global__ __launch_bounds__(256) void silu_kernel(const _Float16* __restrict__ partial,
                                                   const float* __restrict__ bd,
                                                   const int* __restrict__ taskOfPos,
                                                   _Float16* __restrict__ act) {
    int idx = blockIdx.x * 256 + threadIdx.x;
    int s = idx >> 5;
    int h = (idx & 31) * 8;
    int t = taskOfPos[s];
    floatx4 b0 = *(const floatx4*)(bd + t * DOWN + h);
    floatx4 b1 = *(const floatx4*)(bd + t * DOWN + h + 4);
    float v[8];
    v[0] = b0[0]; v[1] = b0[1]; v[2] = b0[2]; v[3] = b0[3];
    v[4] = b1[0]; v[5] = b1[1]; v[6] = b1[2]; v[7] = b1[3];
#pragma unroll
    for (int kc = 0; kc < KC; kc++) {
        half8 p = *(const half8*)(partial + ((size_t)kc * BATCH + s) * DOWN + h);
#pragma unroll
        for (int j = 0; j < 8; j++) v[j] += (float)p[j];
    }
    half8 o;
#pragma unroll
    for (int j = 0; j < 8; j++) {
        float sv = v[j] / (1.0f + __expf(-v[j]));
        o[j] = (_Float16)sv;
    }
    *(half8*)(act + (size_t)s * DOWN + h) = o;
}

// ---------------- GEMM2: out = x + act @ Wu16[t] + bu --------------------------
// M=64 x N=256 per block, BK=32, 8 ksteps. BOTH operands staged via
// global_load_lds (act rows are pos-contiguous -> affine source, no gather).
__global__ __launch_bounds__(256, 3) void gemm2_kernel(const _Float16* __restrict__ act,
                                                       const _Float16* __restrict__ Wu16,
                                                       const float* __restrict__ bu,
                                                       const float* __restrict__ x,
                                                       const int* __restrict__ taskOff,
                                                       const int* __restrict__ sortedIdx,
                                                       float* __restrict__ out) {
    int nt = blockIdx.x >> 1, z = blockIdx.x & 1, task = blockIdx.y;
    int rowStart = taskOff[task];
    int nrows = taskOff[task + 1] - rowStart;
    if (nrows <= 0) return;

    __shared__ half8 Ah[2][64][4];   // [buf][row][kg^], 4 KB/buf
    __shared__ half8 Bp[2][4][256];  // [buf][kg][n], 16 KB/buf

    int tid = threadIdx.x;
    int wave = tid >> 6, lane = tid & 63, quad = lane >> 4, l15 = lane & 15;
    int ncol0 = nt * 256;

    for (int r0 = z * 64; r0 < nrows; r0 += 128) {
        // source row (clamped) for this lane's A-stage slot: row = wave*16 + lane>>2
        int ar = wave * 16 + (lane >> 2);
        const _Float16* asrc_row =
            act + (size_t)(rowStart + imin(r0 + ar, nrows - 1)) * DOWN +
            ((lane & 3) ^ (ar & 3)) * 8;  // inverse-swizzled chunk

        // ---- prologue: kstep 0 -> buf 0 ----
        {
            const char* tb = (const char*)Wu16 +
                             (((size_t)(task * 16 + nt) * 4) << 15);
#pragma unroll
            for (int i = 0; i < 4; i++)
                async16((char*)(&Bp[0][0][0]) + (wave * 4 + i) * 1024,
                        tb + (wave * 4 + i) * 1024 + lane * 16);
            async16((char*)(&Ah[0][0][0]) + wave * 1024, asrc_row);
        }
        __syncthreads();

        floatx4 acc[4][4];
#pragma unroll
        for (int mi = 0; mi < 4; mi++)
#pragma unroll
            for (int ni = 0; ni < 4; ni++) acc[mi][ni] = (floatx4){0.f, 0.f, 0.f, 0.f};

        int buf = 0;
        for (int ts = 0; ts < 8; ts++) {
            if (ts < 7) {
                int tn = ts + 1;
                const char* tb = (const char*)Wu16 +
                                 (((size_t)(task * 16 + nt) * 4 + (tn >> 1)) << 15) +
                                 ((size_t)(tn & 1) << 14);
#pragma unroll
                for (int i = 0; i < 4; i++)
                    async16((char*)(&Bp[buf ^ 1][0][0]) + (wave * 4 + i) * 1024,
                            tb + (wave * 4 + i) * 1024 + lane * 16);
                async16((char*)(&Ah[buf ^ 1][0][0]) + wave * 1024, asrc_row + tn * 32);
            }
            // ---- compute ----
            half8 a[4], bfr[4];
#pragma unroll
            for (int mi = 0; mi < 4; mi++) {
                int row = mi * 16 + l15;
                a[mi] = Ah[buf][row][quad ^ (row & 3)];
            }
#pragma unroll
            for (int ni = 0; ni < 4; ni++)
                bfr[ni] = Bp[buf][quad][wave * 64 + ni * 16 + l15];
#pragma unroll
            for (int mi = 0; mi < 4; mi++)
#pragma unroll
                for (int ni = 0; ni < 4; ni++)
                    acc[mi][ni] = __builtin_amdgcn_mfma_f32_16x16x32_f16(
                        a[mi], bfr[ni], acc[mi][ni], 0, 0, 0);
            __syncthreads();
            buf ^= 1;
        }
        // ---- epilogue: scatter, bias + fp32 residual ----
#pragma unroll
        for (int mi = 0; mi < 4; mi++) {
#pragma unroll
            for (int reg = 0; reg < 4; reg++) {
                int r = r0 + mi * 16 + quad * 4 + reg;
                if (r < nrows) {
                    int b = sortedIdx[rowStart + r];
                    const float* xr = x + (size_t)b * SIZE;
                    float* outr = out + (size_t)b * SIZE;
#pragma unroll
                    for (int ni = 0; ni < 4; ni++) {
                        int n = ncol0 + wave * 64 + ni * 16 + l15;
                        outr[n] = acc[mi][ni][reg] + bu[task * SIZE + n] + xr[n];
                    }
                }
            }
        }
    }
}

// ================= fallback path (round-1 kernels, used if d_ws too small) =====
__global__ __launch_bounds__(256, 2) void gemm1_fb(const float* __restrict__ x,
                                                   const float* __restrict__ Wd,
                                                   const int* __restrict__ taskOff,
                                                   const int* __restrict__ sortedIdx,
                                                   _Float16* __restrict__ partial) {
    int task = blockIdx.x >> 1, z = blockIdx.x & 1, kc = blockIdx.y;
    int rowStart = taskOff[task];
    int nrows = taskOff[task + 1] - rowStart;
    if (nrows <= 0) return;
    __shared__ half8 A_lds[8][65];
    __shared__ half8 B_lds[8][256];
    int tid = threadIdx.x;
    int wave = tid >> 6, lane = tid & 63, quad = lane >> 4, l15 = lane & 15;
    int kbase0 = kc * KCHUNK;
    const float* Wdt = Wd + (size_t)task * SIZE * DOWN;
    int uswz[4];
#pragma unroll
    for (int i = 0; i < 4; i++) {
        int n = wave * 64 + i * 16 + l15;
        uswz[i] = n ^ ((n >> 3) & 7);
    }
    for (int r0 = z * 64; r0 < nrows; r0 += 128) {
        floatx4 acc[4][4];
#pragma unroll
        for (int mi = 0; mi < 4; mi++)
#pragma unroll
            for (int ni = 0; ni < 4; ni++) acc[mi][ni] = (floatx4){0.f, 0.f, 0.f, 0.f};
        int arow = tid >> 2;
        int asrc = sortedIdx[rowStart + imin(r0 + arow, nrows - 1)];
        const float* xrow = x + (size_t)asrc * SIZE;
        for (int kb = 0; kb < KCHUNK; kb += 64) {
            int kglob = kbase0 + kb;
            floatx4 fa[2][2];
#pragma unroll
            for (int j = 0; j < 2; j++) {
                int kg = ((tid & 3) << 1) | j;
                const float* src = xrow + kglob + kg * 8;
                fa[j][0] = *(const floatx4*)(src);
                fa[j][1] = *(const floatx4*)(src + 4);
            }
            floatx4 fb[2][8];
#pragma unroll
            for (int s = 0; s < 2; s++) {
                int kg = s * 4 + wave;
                const float* src = Wdt + (size_t)(kglob + kg * 8) * DOWN + lane * 4;
#pragma unroll
                for (int j = 0; j < 8; j++) fb[s][j] = *(const floatx4*)(src + (size_t)j * DOWN);
            }
            __syncthreads();
#pragma unroll
            for (int j = 0; j < 2; j++) {
                int kg = ((tid & 3) << 1) | j;
                half8 h;
                h[0] = (_Float16)fa[j][0][0]; h[1] = (_Float16)fa[j][0][1];
                h[2] = (_Float16)fa[j][0][2]; h[3] = (_Float16)fa[j][0][3];
                h[4] = (_Float16)fa[j][1][0]; h[5] = (_Float16)fa[j][1][1];
                h[6] = (_Float16)fa[j][1][2]; h[7] = (_Float16)fa[j][1][3];
                A_lds[kg][arow] = h;
            }
#pragma unroll
            for (int s = 0; s < 2; s++) {
                int kg = s * 4 + wave;
#pragma unroll
                for (int i = 0; i < 4; i++) {
                    half8 h;
#pragma unroll
                    for (int j = 0; j < 8; j++) h[j] = (_Float16)fb[s][j][i];
                    int n = lane * 4 + i;
                    B_lds[kg][n ^ ((n >> 3) & 7)] = h;
                }
            }
            __syncthreads();
#pragma unroll
            for (int ks = 0; ks < 2; ks++) {
                int kg = ks * 4 + quad;
                half8 a[4], b[4];
#pragma unroll
                for (int i = 0; i < 4; i++) a[i] = A_lds[kg][i * 16 + l15];
#pragma unroll
                for (int i = 0; i < 4; i++) b[i] = B_lds[kg][uswz[i]];
#pragma unroll
                for (int mi = 0; mi < 4; mi++)
#pragma unroll
                    for (int ni = 0; ni < 4; ni++)
                        acc[mi][ni] = __builtin_amdgcn_mfma_f32_16x16x32_f16(
                            a[mi], b[ni], acc[mi][ni], 0, 0, 0);
            }
        }
#pragma unroll
        for (int mi = 0; mi < 4; mi++) {
#pragma unroll
            for (int reg = 0; reg < 4; reg++) {
                int r = r0 + mi * 16 + quad * 4 + reg;
                if (r < nrows) {
                    size_t rowoff = ((size_t)kc * BATCH + (rowStart + r)) * DOWN;
#pragma unroll
                    for (int ni = 0; ni < 4; ni++) {
                        int h = wave * 64 + ni * 16 + l15;
                        partial[rowoff + h] = (_Float16)acc[mi][ni][reg];
                    }
                }
            }
        }
    }
}

__global__ __launch_bounds__(256, 2) void gemm2_fb(const _Float16* __restrict__ act,
                                                   const float* __restrict__ Wu,
                                                   const float* __restrict__ bu,
                                                   const float* __restrict__ x,
                                                   const int* __restrict__ taskOff,
                                                   const int* __restrict__ sortedIdx,
                                                   float* __restrict__ out) {
    int nt = blockIdx.x >> 1, z = blockIdx.x & 1, task = blockIdx.y;
    int rowStart = taskOff[task];
    int nrows = taskOff[task + 1] - rowStart;
    if (nrows <= 0) return;
    __shared__ half8 A_lds[32][64];
    __shared__ half8 B_lds[4][64][8];
    int tid = threadIdx.x;
    int wave = tid >> 6, lane = tid & 63, quad = lane >> 4, l15 = lane & 15;
    int ncol0 = nt * 256;
    const float* Wut = Wu + (size_t)task * DOWN * SIZE;
    int arow = tid >> 2, ac = tid & 3;
    for (int r0 = z * 64; r0 < nrows; r0 += 128) {
        __syncthreads();
        {
            int s_a = rowStart + imin(r0 + arow, nrows - 1);
            const _Float16* ar = act + (size_t)s_a * DOWN;
#pragma unroll
            for (int j = 0; j < 8; j++) {
                int kg = j * 4 + ac;
                A_lds[kg][arow] = *(const half8*)(ar + kg * 8);
            }
        }
        __syncthreads();
        floatx4 acc[4][4];
#pragma unroll
        for (int mi = 0; mi < 4; mi++)
#pragma unroll
            for (int ni = 0; ni < 4; ni++) acc[mi][ni] = (floatx4){0.f, 0.f, 0.f, 0.f};
        for (int kb = 0; kb < DOWN; kb += 64) {
            floatx4 fb[16];
            const float* bs =
                Wut + (size_t)(kb + quad * 16) * SIZE + ncol0 + wave * 64 + l15 * 4;
#pragma unroll
            for (int j = 0; j < 16; j++) fb[j] = *(const floatx4*)(bs + (size_t)j * SIZE);
#pragma unroll
            for (int g = 0; g < 2; g++)
#pragma unroll
                for (int n2 = 0; n2 < 4; n2++) {
                    half8 h;
#pragma unroll
                    for (int e = 0; e < 8; e++) h[e] = (_Float16)fb[g * 8 + e][n2];
                    B_lds[wave][l15 * 4 + n2][quad * 2 + g] = h;
                }
#pragma unroll
            for (int ks = 0; ks < 2; ks++) {
                int kg = (kb >> 3) + ks * 4 + quad;
                half8 a[4], b[4];
#pragma unroll
                for (int i = 0; i < 4; i++) a[i] = A_lds[kg][i * 16 + l15];
#pragma unroll
                for (int i = 0; i < 4; i++) b[i] = B_lds[wave][i * 16 + l15][ks * 4 + quad];
#pragma unroll
                for (int mi = 0; mi < 4; mi++)
#pragma unroll
                    for (int ni = 0; ni < 4; ni++)
                        acc[mi][ni] = __builtin_amdgcn_mfma_f32_16x16x32_f16(
                            a[mi], b[ni], acc[mi][ni], 0, 0, 0);
            }
        }
#pragma unroll
        for (int mi = 0; mi < 4; mi++) {
#pragma unroll
            for (int reg = 0; reg < 4; reg++) {
                int r = r0 + mi * 16 + quad * 4 + reg;
                if (r < nrows) {
                    int b = sortedIdx[rowStart + r];
                    const float* xr = x + (size_t)b * SIZE;
                    float* outr = out + (size_t)b * SIZE;
#pragma unroll
                    for (int ni = 0; ni < 4; ni++) {
                        int n = ncol0 + wave * 64 + ni * 16 + l15;
                        outr[n] = acc[mi][ni][reg] + bu[task * SIZE + n] + xr[n];
                    }
                }
            }
        }
    }
}

extern "C" void kernel_launch(void* const* d_in, const int* in_sizes, int n_in,
                              void* d_out, int out_size, void* d_ws, size_t ws_size,
                              hipStream_t stream) {
    const float* x       = (const float*)d_in[0];
    const int*   task_id = (const int*)d_in[1];
    const float* Wd      = (const float*)d_in[2];
    const float* bd      = (const float*)d_in[3];
    const float* Wu      = (const float*)d_in[4];
    const float* bu      = (const float*)d_in[5];
    float* out = (float*)d_out;

    size_t need = ((size_t)49 << 20) + 16384;
    if (ws_size >= need) {
        // ws: [0,16M) partial fp16 | [16M,48M) Wu16 | [48M,49M) act | idx arrays
        // d_out holds Wd16 (32 MB) from prep through gemm1; dead before gemm2
        // overwrites d_out with the final output.
        char* wsb = (char*)d_ws;
        _Float16* partial = (_Float16*)wsb;
        _Float16* Wu16    = (_Float16*)(wsb + ((size_t)16 << 20));
        _Float16* act     = (_Float16*)(wsb + ((size_t)48 << 20));
        int* taskOff   = (int*)(wsb + ((size_t)49 << 20));
        int* sortedIdx = taskOff + 32;
        int* taskOfPos = sortedIdx + BATCH;
        _Float16* Wd16 = (_Float16*)d_out;

        prep_kernel<<<2049, 256, 0, stream>>>(task_id, taskOff, sortedIdx, taskOfPos,
                                              Wd, Wu, Wd16, Wu16);
        gemm1_kernel<<<dim3(NTASK * 2, KC), 256, 0, stream>>>(x, Wd16, taskOff,
                                                              sortedIdx, partial);
        silu_kernel<<<(BATCH * DOWN / 8) / 256, 256, 0, stream>>>(partial, bd,
                                                                  taskOfPos, act);
        gemm2_kernel<<<dim3(32, NTASK), 256, 0, stream>>>(act, Wu16, bu, x, taskOff,
                                                          sortedIdx, out);
    } else {
        // fallback: round-1 layout (partial in d_out, act+idx in ws)
        _Float16* partial = (_Float16*)d_out;
        _Float16* act     = (_Float16*)d_ws;
        int* taskOff   = (int*)(act + (size_t)BATCH * DOWN);
        int* sortedIdx = taskOff + 32;
        int* taskOfPos = sortedIdx + BATCH;
        sort_kernel<<<1, 256, 0, stream>>>(task_id, taskOff, sortedIdx, taskOfPos);
        gemm1_fb<<<dim3(NTASK * 2, KC), 256, 0, stream>>>(x, Wd, taskOff, sortedIdx,
                                                          partial);
        silu_kernel<<<(BATCH * DOWN / 8) / 256, 256, 0, stream>>>(partial, bd,
                                                                  taskOfPos, act);
        gemm2_fb<<<dim3(32, NTASK), 256, 0, stream>>>(act, Wu, bu, x, taskOff,
                                                      sortedIdx, out);
    }
}

// Round 4
// 255.298 us; speedup vs baseline: 1.0892x; 1.0892x over previous
//
#include <hip/hip_runtime.h>

#define BATCH 2048
#define SIZE 4096
#define DOWN 256
#define NTASK 16
#define KC 16
#define KCHUNK (SIZE / KC)  // 256
#define BK 16               // k per pipeline step

typedef _Float16 half4 __attribute__((ext_vector_type(4)));
typedef float floatx4 __attribute__((ext_vector_type(4)));

__device__ __forceinline__ int imin(int a, int b) { return a < b ? a : b; }

// async global->LDS: dest = wave-uniform LDS base + lane*16 (HW); src per-lane.
__device__ __forceinline__ void async16(void* lds, const void* g) {
    __builtin_amdgcn_global_load_lds((const __attribute__((address_space(1))) unsigned int*)g,
                                     (__attribute__((address_space(3))) unsigned int*)lds,
                                     16, 0, 0);
}

// Counted waits (T4): NEVER drain vmcnt to 0 in steady state. "memory" clobber
// orders the following ds_reads; sched_barrier(0) fences compiler motion (#18).
#define WAITV5() asm volatile("s_waitcnt vmcnt(5)" ::: "memory")
#define WAITV0() asm volatile("s_waitcnt vmcnt(0)" ::: "memory")
#define SBAR()                             \
    do {                                   \
        __builtin_amdgcn_sched_barrier(0); \
        __builtin_amdgcn_s_barrier();      \
        __builtin_amdgcn_sched_barrier(0); \
    } while (0)

// ---------------- counting sort: group samples by task ----------------
__global__ __launch_bounds__(256) void sort_kernel(const int* __restrict__ task_id,
                                                   int* __restrict__ taskOff,
                                                   int* __restrict__ sortedIdx,
                                                   int* __restrict__ taskOfPos) {
    __shared__ int cnt[NTASK];
    __shared__ int base[NTASK + 1];
    __shared__ int cur[NTASK];
    int tid = threadIdx.x;
    if (tid < NTASK) cnt[tid] = 0;
    __syncthreads();
    for (int i = tid; i < BATCH; i += 256) atomicAdd(&cnt[task_id[i]], 1);
    __syncthreads();
    if (tid == 0) {
        int s = 0;
        for (int t = 0; t < NTASK; t++) { base[t] = s; s += cnt[t]; }
        base[NTASK] = s;
    }
    __syncthreads();
    if (tid < NTASK) { cur[tid] = base[tid]; taskOff[tid] = base[tid]; }
    if (tid == 0) taskOff[NTASK] = BATCH;
    __syncthreads();
    for (int i = tid; i < BATCH; i += 256) {
        int t = task_id[i];
        int p = atomicAdd(&cur[t], 1);
        sortedIdx[p] = i;
        taskOfPos[p] = t;
    }
}

// ---------------- GEMM1: partial[kc][pos][h] = x[rows(t)] @ Wd[t] ------------
// M=64 x N=256, BK=16, 16 ksteps/kc-chunk. fp32 operands staged raw via
// global_load_lds into a 3-buffer ring; fp16 convert at fragment read.
// Steady loop: WAIT vmcnt(5) -> raw s_barrier -> issue(t+2) -> compute(t).
// Loads for step t+1 stay in flight ACROSS the barrier (T3+T4).
__global__ __launch_bounds__(256, 2) void gemm1_kernel(const float* __restrict__ x,
                                                       const float* __restrict__ Wd,
                                                       const int* __restrict__ taskOff,
                                                       const int* __restrict__ sortedIdx,
                                                       _Float16* __restrict__ partial) {
    int task = blockIdx.x >> 1, z = blockIdx.x & 1, kc = blockIdx.y;
    int rowStart = taskOff[task];
    int nrows = taskOff[task + 1] - rowStart;
    if (nrows <= 0) return;

    __shared__ float Bf[3][BK][DOWN];   // 48 KB: [buf][k][n]
    __shared__ float Af[3][4][64][4];   // 12 KB: [buf][kchunk][row][4k]

    int tid = threadIdx.x;
    int wave = tid >> 6, lane = tid & 63, quad = lane >> 4, l15 = lane & 15;
    int kbase = kc * KCHUNK;
    const float* Wdt = Wd + (size_t)task * SIZE * DOWN + (size_t)kbase * DOWN;

    for (int r0 = z * 64; r0 < nrows; r0 += 128) {
        int sidx = sortedIdx[rowStart + imin(r0 + lane, nrows - 1)];
        const float* aptr = x + (size_t)sidx * SIZE + kbase;  // per-lane row ptr
        const float* bptr = Wdt + (size_t)(wave * 4) * DOWN + lane * 4;

        // 5 glds per wave per kstep (uniform across waves -> vmcnt math holds)
#define G1_ISSUE(T, BI)                                                  \
        {                                                                \
            const float* bs_ = bptr + (size_t)(T) * BK * DOWN;           \
            async16(&Bf[BI][wave * 4 + 0][0], bs_);                      \
            async16(&Bf[BI][wave * 4 + 1][0], bs_ + DOWN);               \
            async16(&Bf[BI][wave * 4 + 2][0], bs_ + 2 * DOWN);           \
            async16(&Bf[BI][wave * 4 + 3][0], bs_ + 3 * DOWN);           \
            async16(&Af[BI][wave][0][0], aptr + (T) * BK + wave * 4);    \
        }

        floatx4 acc[4][4];
#pragma unroll
        for (int mi = 0; mi < 4; mi++)
#pragma unroll
            for (int ni = 0; ni < 4; ni++) acc[mi][ni] = (floatx4){0.f, 0.f, 0.f, 0.f};

        G1_ISSUE(0, 0);
        G1_ISSUE(1, 1);
        int buf = 0, nb = 2;
        for (int t = 0; t < 16; t++) {
            if (t < 15) { WAITV5(); } else { WAITV0(); }
            SBAR();
            if (t < 14) { G1_ISSUE(t + 2, nb); }
            // ---- compute kstep t from buf ----
            half4 a[4], b[4];
#pragma unroll
            for (int mi = 0; mi < 4; mi++) {
                floatx4 v = *(const floatx4*)&Af[buf][quad][mi * 16 + l15][0];
                half4 h;
                h[0] = (_Float16)v[0]; h[1] = (_Float16)v[1];
                h[2] = (_Float16)v[2]; h[3] = (_Float16)v[3];
                a[mi] = h;
            }
#pragma unroll
            for (int ni = 0; ni < 4; ni++) {
                int n = wave * 64 + ni * 16 + l15;
                half4 h;
#pragma unroll
                for (int e = 0; e < 4; e++) h[e] = (_Float16)Bf[buf][quad * 4 + e][n];
                b[ni] = h;
            }
#pragma unroll
            for (int mi = 0; mi < 4; mi++)
#pragma unroll
                for (int ni = 0; ni < 4; ni++)
                    acc[mi][ni] = __builtin_amdgcn_mfma_f32_16x16x16f16(
                        a[mi], b[ni], acc[mi][ni], 0, 0, 0);
            buf = (buf == 2) ? 0 : buf + 1;
            nb = (nb == 2) ? 0 : nb + 1;
        }
        SBAR();  // tile-end: protect ring bufs before next tile's issues
#undef G1_ISSUE
        // ---- epilogue: partial[kc][rowStart+r][h], fp16 ----
#pragma unroll
        for (int mi = 0; mi < 4; mi++) {
#pragma unroll
            for (int reg = 0; reg < 4; reg++) {
                int r = r0 + mi * 16 + quad * 4 + reg;
                if (r < nrows) {
                    size_t rowoff = ((size_t)kc * BATCH + (rowStart + r)) * DOWN;
#pragma unroll
                    for (int ni = 0; ni < 4; ni++) {
                        int h = wave * 64 + ni * 16 + l15;
                        partial[rowoff + h] = (_Float16)acc[mi][ni][reg];
                    }
                }
            }
        }
    }
}

// ---------------- SiLU: act[s][h] = silu(sum_kc partial + bd), fp32 out -------
__global__ __launch_bounds__(256) void silu_kernel(const _Float16* __restrict__ partial,
                                                   const float* __restrict__ bd,
                                                   const int* __restrict__ taskOfPos,
                                                   float* __restrict__ act) {
    typedef _Float16 half8 __attribute__((ext_vector_type(8)));
    int idx = blockIdx.x * 256 + threadIdx.x;  // BATCH*DOWN/8 threads
    int s = idx >> 5;
    int h = (idx & 31) * 8;
    int t = taskOfPos[s];
    floatx4 b0 = *(const floatx4*)(bd + t * DOWN + h);
    floatx4 b1 = *(const floatx4*)(bd + t * DOWN + h + 4);
    float v[8];
    v[0] = b0[0]; v[1] = b0[1]; v[2] = b0[2]; v[3] = b0[3];
    v[4] = b1[0]; v[5] = b1[1]; v[6] = b1[2]; v[7] = b1[3];
#pragma unroll
    for (int kc = 0; kc < KC; kc++) {
        half8 p = *(const half8*)(partial + ((size_t)kc * BATCH + s) * DOWN + h);
#pragma unroll
        for (int j = 0; j < 8; j++) v[j] += (float)p[j];
    }
    floatx4 o0, o1;
#pragma unroll
    for (int j = 0; j < 4; j++) o0[j] = v[j] / (1.0f + __expf(-v[j]));
#pragma unroll
    for (int j = 0; j < 4; j++) o1[j] = v[j + 4] / (1.0f + __expf(-v[j + 4]));
    *(floatx4*)(act + (size_t)s * DOWN + h) = o0;
    *(floatx4*)(act + (size_t)s * DOWN + h + 4) = o1;
}

// ---------------- GEMM2: out = x + act @ Wu[t] + bu ---------------------------
// Same pipelined skeleton; A = fp32 act rows (pos-contiguous), B = fp32 Wu.
__global__ __launch_bounds__(256, 2) void gemm2_kernel(const float* __restrict__ act,
                                                       const float* __restrict__ Wu,
                                                       const float* __restrict__ bu,
                                                       const float* __restrict__ x,
                                                       const int* __restrict__ taskOff,
                                                       const int* __restrict__ sortedIdx,
                                                       float* __restrict__ out) {
    int nt = blockIdx.x >> 1, z = blockIdx.x & 1, task = blockIdx.y;
    int rowStart = taskOff[task];
    int nrows = taskOff[task + 1] - rowStart;
    if (nrows <= 0) return;

    __shared__ float Bf[3][BK][256];
    __shared__ float Af[3][4][64][4];

    int tid = threadIdx.x;
    int wave = tid >> 6, lane = tid & 63, quad = lane >> 4, l15 = lane & 15;
    int ncol0 = nt * 256;
    const float* Wut = Wu + (size_t)task * DOWN * SIZE + ncol0;

    for (int r0 = z * 64; r0 < nrows; r0 += 128) {
        const float* aptr = act + (size_t)(rowStart + imin(r0 + lane, nrows - 1)) * DOWN;
        const float* bptr = Wut + (size_t)(wave * 4) * SIZE + lane * 4;

#define G2_ISSUE(T, BI)                                                  \
        {                                                                \
            const float* bs_ = bptr + (size_t)(T) * BK * SIZE;           \
            async16(&Bf[BI][wave * 4 + 0][0], bs_);                      \
            async16(&Bf[BI][wave * 4 + 1][0], bs_ + SIZE);               \
            async16(&Bf[BI][wave * 4 + 2][0], bs_ + 2 * SIZE);           \
            async16(&Bf[BI][wave * 4 + 3][0], bs_ + 3 * SIZE);           \
            async16(&Af[BI][wave][0][0], aptr + (T) * BK + wave * 4);    \
        }

        floatx4 acc[4][4];
#pragma unroll
        for (int mi = 0; mi < 4; mi++)
#pragma unroll
            for (int ni = 0; ni < 4; ni++) acc[mi][ni] = (floatx4){0.f, 0.f, 0.f, 0.f};

        G2_ISSUE(0, 0);
        G2_ISSUE(1, 1);
        int buf = 0, nb = 2;
        for (int t = 0; t < 16; t++) {
            if (t < 15) { WAITV5(); } else { WAITV0(); }
            SBAR();
            if (t < 14) { G2_ISSUE(t + 2, nb); }
            half4 a[4], b[4];
#pragma unroll
            for (int mi = 0; mi < 4; mi++) {
                floatx4 v = *(const floatx4*)&Af[buf][quad][mi * 16 + l15][0];
                half4 h;
                h[0] = (_Float16)v[0]; h[1] = (_Float16)v[1];
                h[2] = (_Float16)v[2]; h[3] = (_Float16)v[3];
                a[mi] = h;
            }
#pragma unroll
            for (int ni = 0; ni < 4; ni++) {
                int n = wave * 64 + ni * 16 + l15;
                half4 h;
#pragma unroll
                for (int e = 0; e < 4; e++) h[e] = (_Float16)Bf[buf][quad * 4 + e][n];
                b[ni] = h;
            }
#pragma unroll
            for (int mi = 0; mi < 4; mi++)
#pragma unroll
                for (int ni = 0; ni < 4; ni++)
                    acc[mi][ni] = __builtin_amdgcn_mfma_f32_16x16x16f16(
                        a[mi], b[ni], acc[mi][ni], 0, 0, 0);
            buf = (buf == 2) ? 0 : buf + 1;
            nb = (nb == 2) ? 0 : nb + 1;
        }
        SBAR();
#undef G2_ISSUE
        // ---- epilogue: scatter to original rows, add bias + fp32 residual ----
#pragma unroll
        for (int mi = 0; mi < 4; mi++) {
#pragma unroll
            for (int reg = 0; reg < 4; reg++) {
                int r = r0 + mi * 16 + quad * 4 + reg;
                if (r < nrows) {
                    int b = sortedIdx[rowStart + r];
                    const float* xr = x + (size_t)b * SIZE;
                    float* outr = out + (size_t)b * SIZE;
#pragma unroll
                    for (int ni = 0; ni < 4; ni++) {
                        int n = ncol0 + wave * 64 + ni * 16 + l15;
                        outr[n] = acc[mi][ni][reg] + bu[task * SIZE + n] + xr[n];
                    }
                }
            }
        }
    }
}

extern "C" void kernel_launch(void* const* d_in, const int* in_sizes, int n_in,
                              void* d_out, int out_size, void* d_ws, size_t ws_size,
                              hipStream_t stream) {
    const float* x       = (const float*)d_in[0];
    const int*   task_id = (const int*)d_in[1];
    const float* Wd      = (const float*)d_in[2];
    const float* bd      = (const float*)d_in[3];
    const float* Wu      = (const float*)d_in[4];
    const float* bu      = (const float*)d_in[5];
    float* out = (float*)d_out;

    // partial (16 MB fp16) lives in d_out: dead before gemm2, which overwrites
    // every byte of d_out. act (fp32, 2 MB) + index arrays live in d_ws.
    _Float16* partial = (_Float16*)d_out;
    float* act        = (float*)d_ws;                       // BATCH*DOWN fp32 = 2 MB
    int* taskOff   = (int*)(act + (size_t)BATCH * DOWN);
    int* sortedIdx = taskOff + 32;
    int* taskOfPos = sortedIdx + BATCH;

    sort_kernel<<<1, 256, 0, stream>>>(task_id, taskOff, sortedIdx, taskOfPos);
    gemm1_kernel<<<dim3(NTASK * 2, KC), 256, 0, stream>>>(x, Wd, taskOff, sortedIdx,
                                                          partial);
    silu_kernel<<<(BATCH * DOWN / 8) / 256, 256, 0, stream>>>(partial, bd, taskOfPos,
                                                              act);
    gemm2_kernel<<<dim3(32, NTASK), 256, 0, stream>>>(act, Wu, bu, x, taskOff,
                                                      sortedIdx, out);
}

// Round 5
// 242.377 us; speedup vs baseline: 1.1473x; 1.0533x over previous
//
#include <hip/hip_runtime.h>

#define BATCH 2048
#define SIZE 4096
#define DOWN 256
#define NTASK 16
#define KC 8
#define KCHUNK (SIZE / KC)  // 512

typedef _Float16 half8 __attribute__((ext_vector_type(8)));
typedef float floatx4 __attribute__((ext_vector_type(4)));

__device__ __forceinline__ int imin(int a, int b) { return a < b ? a : b; }
// 16B-granular XOR swizzle: spreads bank groups for b128 LDS writes/reads
__device__ __forceinline__ int uswz(int n) { return n ^ ((n >> 3) & 7); }

// ---------------- counting sort: group samples by task ----------------
__global__ __launch_bounds__(256) void sort_kernel(const int* __restrict__ task_id,
                                                   int* __restrict__ taskOff,
                                                   int* __restrict__ sortedIdx,
                                                   int* __restrict__ taskOfPos) {
    __shared__ int cnt[NTASK];
    __shared__ int base[NTASK + 1];
    __shared__ int cur[NTASK];
    int tid = threadIdx.x;
    if (tid < NTASK) cnt[tid] = 0;
    __syncthreads();
    for (int i = tid; i < BATCH; i += 256) atomicAdd(&cnt[task_id[i]], 1);
    __syncthreads();
    if (tid == 0) {
        int s = 0;
        for (int t = 0; t < NTASK; t++) { base[t] = s; s += cnt[t]; }
        base[NTASK] = s;
    }
    __syncthreads();
    if (tid < NTASK) { cur[tid] = base[tid]; taskOff[tid] = base[tid]; }
    if (tid == 0) taskOff[NTASK] = BATCH;
    __syncthreads();
    for (int i = tid; i < BATCH; i += 256) {
        int t = task_id[i];
        int p = atomicAdd(&cur[t], 1);
        sortedIdx[p] = i;
        taskOfPos[p] = t;
    }
}

// ---------------- GEMM1: partial[kc][s][h] = x[rows(t)] @ Wd[t] (K-chunked) ----
// grid (NTASK*2, KC): x = task*2 + z (row split). block 256 thr, tile M=64 x N=256,
// wave n-strip 64, BK=64. Environment is streaming-rate capped (~2.2 TB/s across
// 7 structure variants, incl. pure copy) -> byte-minimal simple structure wins.
__global__ __launch_bounds__(256, 2) void gemm1_kernel(const float* __restrict__ x,
                                                       const float* __restrict__ Wd,
                                                       const int* __restrict__ taskOff,
                                                       const int* __restrict__ sortedIdx,
                                                       _Float16* __restrict__ partial) {
    int task = blockIdx.x >> 1, z = blockIdx.x & 1, kc = blockIdx.y;
    int rowStart = taskOff[task];
    int nrows = taskOff[task + 1] - rowStart;
    if (nrows <= 0) return;

    __shared__ half8 A_lds[8][65];    // [kgroup][row], k-pack-8 (+1 pad)
    __shared__ half8 B_lds[8][256];   // [kgroup][swizzled n]

    int tid = threadIdx.x;
    int wave = tid >> 6, lane = tid & 63, quad = lane >> 4, l15 = lane & 15;
    int kbase0 = kc * KCHUNK;
    const float* Wdt = Wd + (size_t)task * SIZE * DOWN;

    // precomputed swizzled B-fragment read offsets (n = wave*64 + i*16 + l15)
    int bswz[4];
#pragma unroll
    for (int i = 0; i < 4; i++) bswz[i] = uswz(wave * 64 + i * 16 + l15);

    for (int r0 = z * 64; r0 < nrows; r0 += 128) {
        floatx4 acc[4][4];
#pragma unroll
        for (int mi = 0; mi < 4; mi++)
#pragma unroll
            for (int ni = 0; ni < 4; ni++) acc[mi][ni] = (floatx4){0.f, 0.f, 0.f, 0.f};

        int arow = tid >> 2;  // 0..63
        int asrc = sortedIdx[rowStart + imin(r0 + arow, nrows - 1)];
        const float* xrow = x + (size_t)asrc * SIZE;

        for (int kb = 0; kb < KCHUNK; kb += 64) {
            int kglob = kbase0 + kb;
            // ---- issue ALL global loads into registers (before barrier) ----
            floatx4 fa[2][2];
#pragma unroll
            for (int j = 0; j < 2; j++) {
                int kg = ((tid & 3) << 1) | j;
                const float* src = xrow + kglob + kg * 8;
                fa[j][0] = *(const floatx4*)(src);
                fa[j][1] = *(const floatx4*)(src + 4);
            }
            // B: thread owns 8k x 4n for kg = s*4 + wave; per-instr the wave reads
            // a contiguous 1KB slice of a Wd row (fully coalesced 16B/lane)
            floatx4 fb[2][8];
#pragma unroll
            for (int s = 0; s < 2; s++) {
                int kg = s * 4 + wave;
                const float* src = Wdt + (size_t)(kglob + kg * 8) * DOWN + lane * 4;
#pragma unroll
                for (int j = 0; j < 8; j++) fb[s][j] = *(const floatx4*)(src + (size_t)j * DOWN);
            }
            __syncthreads();  // previous compute phase done reading LDS
            // ---- convert + stage to LDS ----
#pragma unroll
            for (int j = 0; j < 2; j++) {
                int kg = ((tid & 3) << 1) | j;
                half8 h;
                h[0] = (_Float16)fa[j][0][0]; h[1] = (_Float16)fa[j][0][1];
                h[2] = (_Float16)fa[j][0][2]; h[3] = (_Float16)fa[j][0][3];
                h[4] = (_Float16)fa[j][1][0]; h[5] = (_Float16)fa[j][1][1];
                h[6] = (_Float16)fa[j][1][2]; h[7] = (_Float16)fa[j][1][3];
                A_lds[kg][arow] = h;
            }
#pragma unroll
            for (int s = 0; s < 2; s++) {
                int kg = s * 4 + wave;
#pragma unroll
                for (int i = 0; i < 4; i++) {
                    half8 h;
#pragma unroll
                    for (int j = 0; j < 8; j++) h[j] = (_Float16)fb[s][j][i];
                    B_lds[kg][uswz(lane * 4 + i)] = h;
                }
            }
            __syncthreads();
            // ---- MFMA ----
#pragma unroll
            for (int ks = 0; ks < 2; ks++) {
                int kg = ks * 4 + quad;
                half8 a[4], b[4];
#pragma unroll
                for (int i = 0; i < 4; i++) a[i] = A_lds[kg][i * 16 + l15];
#pragma unroll
                for (int i = 0; i < 4; i++) b[i] = B_lds[kg][bswz[i]];
#pragma unroll
                for (int mi = 0; mi < 4; mi++)
#pragma unroll
                    for (int ni = 0; ni < 4; ni++)
                        acc[mi][ni] = __builtin_amdgcn_mfma_f32_16x16x32_f16(
                            a[mi], b[ni], acc[mi][ni], 0, 0, 0);
            }
        }
        // epilogue: partial[kc][rowStart+r][h], fp16
#pragma unroll
        for (int mi = 0; mi < 4; mi++) {
#pragma unroll
            for (int reg = 0; reg < 4; reg++) {
                int r = r0 + mi * 16 + quad * 4 + reg;
                if (r < nrows) {
                    size_t rowoff = ((size_t)kc * BATCH + (rowStart + r)) * DOWN;
#pragma unroll
                    for (int ni = 0; ni < 4; ni++) {
                        int h = wave * 64 + ni * 16 + l15;
                        partial[rowoff + h] = (_Float16)acc[mi][ni][reg];
                    }
                }
            }
        }
    }
}

// ---------------- SiLU: act[s][h] = silu(sum_kc partial + bd), half8-vectorized --
__global__ __launch_bounds__(256) void silu_kernel(const _Float16* __restrict__ partial,
                                                   const float* __restrict__ bd,
                                                   const int* __restrict__ taskOfPos,
                                                   _Float16* __restrict__ act) {
    int idx = blockIdx.x * 256 + threadIdx.x;  // BATCH*DOWN/8 = 65536 total
    int s = idx >> 5;                          // 32 half8 chunks per row
    int h = (idx & 31) * 8;
    int t = taskOfPos[s];
    floatx4 b0 = *(const floatx4*)(bd + t * DOWN + h);
    floatx4 b1 = *(const floatx4*)(bd + t * DOWN + h + 4);
    float v[8];
    v[0] = b0[0]; v[1] = b0[1]; v[2] = b0[2]; v[3] = b0[3];
    v[4] = b1[0]; v[5] = b1[1]; v[6] = b1[2]; v[7] = b1[3];
#pragma unroll
    for (int kc = 0; kc < KC; kc++) {
        half8 p = *(const half8*)(partial + ((size_t)kc * BATCH + s) * DOWN + h);
#pragma unroll
        for (int j = 0; j < 8; j++) v[j] += (float)p[j];
    }
    half8 o;
#pragma unroll
    for (int j = 0; j < 8; j++) {
        float sv = v[j] / (1.0f + __expf(-v[j]));
        o[j] = (_Float16)sv;
    }
    *(half8*)(act + (size_t)s * DOWN + h) = o;
}

// ---------------- GEMM2: out = x + act @ Wu[t] + bu ----------------
// grid (SIZE/128, NTASK). block 256 thr, tile M=128 x N=128, waves 2x2,
// K=256, BK=64. out stored non-temporally to keep LLC for weights/partial.
__global__ __launch_bounds__(256, 2) void gemm2_kernel(const _Float16* __restrict__ act,
                                                       const float* __restrict__ Wu,
                                                       const float* __restrict__ bu,
                                                       const float* __restrict__ x,
                                                       const int* __restrict__ taskOff,
                                                       const int* __restrict__ sortedIdx,
                                                       float* __restrict__ out) {
    int nt = blockIdx.x, task = blockIdx.y;
    int rowStart = taskOff[task];
    int nrows = taskOff[task + 1] - rowStart;
    if (nrows <= 0) return;

    __shared__ half8 A_lds[8][129];  // [kgroup][row 0..127] (+1 pad)
    __shared__ half8 B_lds[8][128];  // [kgroup][swizzled n]

    int tid = threadIdx.x;
    int wave = tid >> 6, lane = tid & 63, quad = lane >> 4, l15 = lane & 15;
    int wm = wave >> 1, wn = wave & 1;
    int ncol0 = nt * 128;
    const float* Wut = Wu + (size_t)task * DOWN * SIZE;

    int bswz[4];
#pragma unroll
    for (int i = 0; i < 4; i++) bswz[i] = uswz(wn * 64 + i * 16 + l15);
    int kgB = tid >> 5, nfB = tid & 31;  // B-staging ownership: 8k x 4n per thread

    for (int r0 = 0; r0 < nrows; r0 += 128) {
        floatx4 acc[4][4];
#pragma unroll
        for (int mi = 0; mi < 4; mi++)
#pragma unroll
            for (int ni = 0; ni < 4; ni++) acc[mi][ni] = (floatx4){0.f, 0.f, 0.f, 0.f};

        int arow = tid >> 1;  // 0..127
        int s_a = rowStart + imin(r0 + arow, nrows - 1);
        const _Float16* actrow = act + (size_t)s_a * DOWN;

        for (int kb = 0; kb < DOWN; kb += 64) {
            // ---- issue ALL global loads into registers ----
            half8 ha[4];
#pragma unroll
            for (int j = 0; j < 4; j++) {
                int kg = ((tid & 1) << 2) | j;
                ha[j] = *(const half8*)(actrow + kb + kg * 8);
            }
            floatx4 fb[8];
            const float* src = Wut + (size_t)(kb + kgB * 8) * SIZE + ncol0 + nfB * 4;
#pragma unroll
            for (int j = 0; j < 8; j++) fb[j] = *(const floatx4*)(src + (size_t)j * SIZE);
            __syncthreads();
            // ---- stage to LDS ----
#pragma unroll
            for (int j = 0; j < 4; j++) {
                int kg = ((tid & 1) << 2) | j;
                A_lds[kg][arow] = ha[j];
            }
#pragma unroll
            for (int i = 0; i < 4; i++) {
                half8 h;
#pragma unroll
                for (int j = 0; j < 8; j++) h[j] = (_Float16)fb[j][i];
                B_lds[kgB][uswz(nfB * 4 + i)] = h;
            }
            __syncthreads();
            // ---- MFMA ----
#pragma unroll
            for (int ks = 0; ks < 2; ks++) {
                int kg = ks * 4 + quad;
                half8 a[4], b[4];
#pragma unroll
                for (int i = 0; i < 4; i++) a[i] = A_lds[kg][wm * 64 + i * 16 + l15];
#pragma unroll
                for (int i = 0; i < 4; i++) b[i] = B_lds[kg][bswz[i]];
#pragma unroll
                for (int mi = 0; mi < 4; mi++)
#pragma unroll
                    for (int ni = 0; ni < 4; ni++)
                        acc[mi][ni] = __builtin_amdgcn_mfma_f32_16x16x32_f16(
                            a[mi], b[ni], acc[mi][ni], 0, 0, 0);
            }
        }
        // epilogue: scatter to original rows, add bias + fp32 residual;
        // non-temporal out stores (dead data; keep LLC for weights)
#pragma unroll
        for (int mi = 0; mi < 4; mi++) {
#pragma unroll
            for (int reg = 0; reg < 4; reg++) {
                int r = r0 + wm * 64 + mi * 16 + quad * 4 + reg;
                if (r < nrows) {
                    int b = sortedIdx[rowStart + r];
                    const float* xr = x + (size_t)b * SIZE;
                    float* outr = out + (size_t)b * SIZE;
#pragma unroll
                    for (int ni = 0; ni < 4; ni++) {
                        int n = ncol0 + wn * 64 + ni * 16 + l15;
                        __builtin_nontemporal_store(
                            acc[mi][ni][reg] + bu[task * SIZE + n] + xr[n], outr + n);
                    }
                }
            }
        }
    }
}

extern "C" void kernel_launch(void* const* d_in, const int* in_sizes, int n_in,
                              void* d_out, int out_size, void* d_ws, size_t ws_size,
                              hipStream_t stream) {
    const float* x       = (const float*)d_in[0];
    const int*   task_id = (const int*)d_in[1];
    const float* Wd      = (const float*)d_in[2];
    const float* bd      = (const float*)d_in[3];
    const float* Wu      = (const float*)d_in[4];
    const float* bu      = (const float*)d_in[5];
    float* out = (float*)d_out;

    // partial (8 MB fp16, KC=8) lives in d_out: dead before gemm2 launches, and
    // gemm2 overwrites every byte of d_out. act + index arrays live in d_ws.
    _Float16* partial = (_Float16*)d_out;               // KC*BATCH*DOWN fp16 = 8 MB
    _Float16* act     = (_Float16*)d_ws;                // BATCH*DOWN fp16 = 1 MB
    int* taskOff   = (int*)(act + (size_t)BATCH * DOWN);
    int* sortedIdx = taskOff + 32;
    int* taskOfPos = sortedIdx + BATCH;

    sort_kernel<<<1, 256, 0, stream>>>(task_id, taskOff, sortedIdx, taskOfPos);
    gemm1_kernel<<<dim3(NTASK * 2, KC), 256, 0, stream>>>(x, Wd, taskOff, sortedIdx, partial);
    silu_kernel<<<(BATCH * DOWN / 8) / 256, 256, 0, stream>>>(partial, bd, taskOfPos, act);
    gemm2_kernel<<<dim3(SIZE / 128, NTASK), 256, 0, stream>>>(act, Wu, bu, x, taskOff,
                                                              sortedIdx, out);
}